// Round 18
// baseline (107.380 us; speedup 1.0000x reference)
//
#include <hip/hip_runtime.h>

#define BB 8
#define CL 4096
#define QL 512
#define DD 256

typedef unsigned short u16;
typedef unsigned char u8;
typedef long long i64;
typedef unsigned int u32;
typedef float f32x4 __attribute__((ext_vector_type(4)));
typedef short s16x8 __attribute__((ext_vector_type(8)));

static __device__ __forceinline__ u16 f2bf(float x) {
  unsigned int u = __float_as_uint(x);
  u += 0x7FFFu + ((u >> 16) & 1u);
  return (u16)(u >> 16);
}
static __device__ __forceinline__ float bf2f(u16 h) {
  return __uint_as_float(((unsigned int)h) << 16);
}

// ---------------- K0: prep q (bf16 row-major, fp8 transposed, qw dots) ----
__global__ __launch_bounds__(256) void prep_q_k(
    const float* __restrict__ q, const float* __restrict__ w,
    u16* __restrict__ qbf, u8* __restrict__ qt8, float* __restrict__ qw_g)
{
  __shared__ u16 qs[8][256];
  __shared__ float red[8][32];
  int blk = blockIdx.x;
  int b = blk & 7;
  int j0 = (blk >> 3) * 8;
  int t = threadIdx.x;
  int r = t >> 5;
  int cs = (t & 31) * 8;

  const float* qrow = q + ((size_t)(b * QL + j0 + r)) * DD + cs;
  float4 v0 = *(const float4*)(qrow);
  float4 v1 = *(const float4*)(qrow + 4);
  float4 w0 = *(const float4*)(w + cs);       // w_q
  float4 w1 = *(const float4*)(w + cs + 4);
  float pw = v0.x*w0.x + v0.y*w0.y + v0.z*w0.z + v0.w*w0.w
           + v1.x*w1.x + v1.y*w1.y + v1.z*w1.z + v1.w*w1.w;

  union { u16 u[8]; uint4 v; } pk;
  pk.u[0]=f2bf(v0.x); pk.u[1]=f2bf(v0.y); pk.u[2]=f2bf(v0.z); pk.u[3]=f2bf(v0.w);
  pk.u[4]=f2bf(v1.x); pk.u[5]=f2bf(v1.y); pk.u[6]=f2bf(v1.z); pk.u[7]=f2bf(v1.w);

  *(uint4*)(qbf + ((size_t)(b * QL + j0 + r)) * DD + cs) = pk.v;
  *(uint4*)(&qs[r][cs]) = pk.v;
  red[r][t & 31] = pw;
  __syncthreads();

  if (t < 8) {
    float s = 0.f;
    #pragma unroll
    for (int k = 0; k < 32; ++k) s += red[t][k];
    qw_g[b * QL + j0 + t] = s;
  }

  int d = t;
  float f[8];
  #pragma unroll
  for (int jj = 0; jj < 8; ++jj) f[jj] = bf2f(qs[jj][d]);
  unsigned int lo = __builtin_amdgcn_cvt_pk_fp8_f32(f[0], f[1], 0u, false);
  lo = __builtin_amdgcn_cvt_pk_fp8_f32(f[2], f[3], lo, true);
  unsigned int hi = __builtin_amdgcn_cvt_pk_fp8_f32(f[4], f[5], 0u, false);
  hi = __builtin_amdgcn_cvt_pk_fp8_f32(f[6], f[7], hi, true);
  *(unsigned int*)(qt8 + ((size_t)(b * DD + d)) * QL + j0) = lo;
  *(unsigned int*)(qt8 + ((size_t)(b * DD + d)) * QL + j0 + 4) = hi;
}

// ---------------- K1: 32-row tile, 1024 blocks -> 4 blocks/CU -------------
// R16 structure with halved tile: LDS ~20.4 KB, regs ~halved; grid supplies
// 4 independent block-contexts per CU for latency hiding.
__global__ __launch_bounds__(512, 4) void attn_main_k(
    const float* __restrict__ c, const float* __restrict__ w,
    const u16* __restrict__ qbf, const u8* __restrict__ qt8,
    const float* __restrict__ qw_g,
    float* __restrict__ pm_g, float* __restrict__ z_g,
    float* __restrict__ part_g, float* __restrict__ out)
{
  __shared__ u8 pool8[32 * 512];     // cm bf16 view [32][256] / P fp8 [32][512]
  __shared__ float qw_s[QL];
  __shared__ float cw_s[32];
  __shared__ float red_m[32][8];     // [row][wave]
  __shared__ float red_z[32][8];

  u16* cm = (u16*)pool8;

  int t = threadIdx.x;
  int blk = blockIdx.x;
  int b = blk & 7;
  int tile = blk >> 3;               // 0..127
  int it0 = tile * 32;

  int wv = t >> 6;                   // 0..7
  int ln = t & 63;
  int lr = ln & 15;
  int lg = ln >> 4;
  int jc = wv * 64;                  // GEMM1 j-chunk
  int aswz = (lr & 7) << 3;

  // ---- staging: c tile -> cm bf16 (swizzled), cw dots ----
  {
    int r = t >> 4;                  // 0..31
    int cg = (t & 15) * 16;          // 16 cols per thread
    int swz = (r & 7) << 3;
    const float* crow = c + ((size_t)(b * CL + it0 + r)) * DD + cg;
    float pcw = 0.f;
    #pragma unroll
    for (int u = 0; u < 16; u += 4) {
      f32x4 cv  = *(const f32x4*)(crow + u);
      f32x4 wcv = *(const f32x4*)(w + DD + cg + u);      // w_c
      f32x4 wmv = *(const f32x4*)(w + 2 * DD + cg + u);  // w_m
      pcw += cv[0]*wcv[0] + cv[1]*wcv[1] + cv[2]*wcv[2] + cv[3]*wcv[3];
      ushort4 hv;
      hv.x = f2bf(cv[0] * wmv[0]); hv.y = f2bf(cv[1] * wmv[1]);
      hv.z = f2bf(cv[2] * wmv[2]); hv.w = f2bf(cv[3] * wmv[3]);
      *(ushort4*)(&cm[r * 256 + ((cg + u) ^ swz)]) = hv;
    }
    pcw += __shfl_xor(pcw, 1);
    pcw += __shfl_xor(pcw, 2);
    pcw += __shfl_xor(pcw, 4);
    pcw += __shfl_xor(pcw, 8);
    if ((t & 15) == 0) cw_s[r] = pcw;
    qw_s[t] = qw_g[b * QL + t];
  }
  __syncthreads();   // bar 1: cm/cw/qw ready

  // ---- GEMM1 (swapped): acc[m][n][rr] = S'[i=m*16+lr][j=jc+n*16+lg*4+rr] --
  f32x4 acc[2][4];
  #pragma unroll
  for (int m = 0; m < 2; ++m)
    #pragma unroll
    for (int n = 0; n < 4; ++n) acc[m][n] = (f32x4){0.f, 0.f, 0.f, 0.f};

  const u16* qb = qbf + (size_t)b * QL * DD + (size_t)(jc + lr) * DD + lg * 8;
  #pragma unroll
  for (int kk = 0; kk < 8; ++kk) {
    s16x8 a[2];
    #pragma unroll
    for (int m = 0; m < 2; ++m)
      a[m] = *(const s16x8*)(&cm[(m * 16 + lr) * 256 + ((kk * 32 + lg * 8) ^ aswz)]);
    #pragma unroll
    for (int nh = 0; nh < 4; nh += 2) {
      s16x8 bq0 = *(const s16x8*)(qb + (size_t)(nh * 16) * DD + kk * 32);
      s16x8 bq1 = *(const s16x8*)(qb + (size_t)((nh + 1) * 16) * DD + kk * 32);
      #pragma unroll
      for (int m = 0; m < 2; ++m) {
        acc[m][nh]     = __builtin_amdgcn_mfma_f32_16x16x32_bf16(bq0, a[m], acc[m][nh], 0, 0, 0);
        acc[m][nh + 1] = __builtin_amdgcn_mfma_f32_16x16x32_bf16(bq1, a[m], acc[m][nh + 1], 0, 0, 0);
      }
    }
  }

  // ---- merged softmax (no-max): bias, exp in-register, per-wave partials -
  #pragma unroll
  for (int m = 0; m < 2; ++m) {
    float mx = -1e30f;
    float s = 0.f;
    #pragma unroll
    for (int n = 0; n < 4; ++n) {
      f32x4 qq = *(const f32x4*)(&qw_s[jc + n * 16 + lg * 4]);
      #pragma unroll
      for (int rr = 0; rr < 4; ++rr) {
        float sv = acc[m][n][rr] + qq[rr];
        mx = fmaxf(mx, sv);
        float e = __expf(sv);
        acc[m][n][rr] = e;
        s += e;
      }
    }
    mx = fmaxf(mx, __shfl_xor(mx, 16));
    mx = fmaxf(mx, __shfl_xor(mx, 32));
    s += __shfl_xor(s, 16);
    s += __shfl_xor(s, 32);
    if (lg == 0) { red_m[m * 16 + lr][wv] = mx; red_z[m * 16 + lr][wv] = s; }
  }
  __syncthreads();   // bar 2: cm reads done -> pool reusable as P

  // ---- P-write: fp8 packed (4 consecutive j per dword), swizzled ----
  #pragma unroll
  for (int m = 0; m < 2; ++m) {
    int row = m * 16 + lr;
    size_t rb = (size_t)row * 512;
    #pragma unroll
    for (int n = 0; n < 4; ++n) {
      unsigned int p4 = __builtin_amdgcn_cvt_pk_fp8_f32(acc[m][n][0], acc[m][n][1], 0u, false);
      p4 = __builtin_amdgcn_cvt_pk_fp8_f32(acc[m][n][2], acc[m][n][3], p4, true);
      *(unsigned int*)(pool8 + rb + (((unsigned)(jc + n * 16 + lg * 4)) ^ aswz)) = p4;
    }
  }
  __syncthreads();   // bar 3: P ready

  // ---- GEMM2 (fp8, swapped): o2[m][n] = c2q[i=m*16+lr][d=dc+n*16+lg*4..] -
  f32x4 o2[2][2];
  #pragma unroll
  for (int m = 0; m < 2; ++m)
    #pragma unroll
    for (int n = 0; n < 2; ++n) o2[m][n] = (f32x4){0.f, 0.f, 0.f, 0.f};

  int dc = wv * 32;
  const u8* qt = qt8 + (size_t)b * DD * QL + (size_t)(dc + lr) * QL + lg * 8;
  #pragma unroll
  for (int kk = 0; kk < 16; ++kk) {
    i64 bv0 = *(const i64*)(qt + kk * 32);
    i64 bv1 = *(const i64*)(qt + (size_t)16 * QL + kk * 32);
    i64 pa[2];
    #pragma unroll
    for (int m = 0; m < 2; ++m)
      pa[m] = *(const i64*)(pool8 + (size_t)(m * 16 + lr) * 512 + (((unsigned)(kk * 32 + lg * 8)) ^ aswz));
    #pragma unroll
    for (int m = 0; m < 2; ++m) {
      o2[m][0] = __builtin_amdgcn_mfma_f32_16x16x32_fp8_fp8(bv0, pa[m], o2[m][0], 0, 0, 0);
      o2[m][1] = __builtin_amdgcn_mfma_f32_16x16x32_fp8_fp8(bv1, pa[m], o2[m][1], 0, 0, 0);
    }
  }

  // ---- per-thread row stats (red_* ordered by bars 2/3) ----
  float invz[2], wgt[2], mt[2];
  float pmx = -1e30f;
  #pragma unroll
  for (int m = 0; m < 2; ++m) {
    int i = m * 16 + lr;
    float4 m0 = *(const float4*)(&red_m[i][0]);
    float4 m1 = *(const float4*)(&red_m[i][4]);
    mt[m] = cw_s[i] + fmaxf(fmaxf(fmaxf(m0.x, m0.y), fmaxf(m0.z, m0.w)),
                            fmaxf(fmaxf(m1.x, m1.y), fmaxf(m1.z, m1.w)));
    pmx = fmaxf(pmx, mt[m]);
    float4 z0 = *(const float4*)(&red_z[i][0]);
    float4 z1 = *(const float4*)(&red_z[i][4]);
    invz[m] = 1.0f / (z0.x + z0.y + z0.z + z0.w + z1.x + z1.y + z1.z + z1.w);
  }
  pmx = fmaxf(pmx, __shfl_xor(pmx, 1));
  pmx = fmaxf(pmx, __shfl_xor(pmx, 2));
  pmx = fmaxf(pmx, __shfl_xor(pmx, 4));
  pmx = fmaxf(pmx, __shfl_xor(pmx, 8));
  float zs = 0.f;
  #pragma unroll
  for (int m = 0; m < 2; ++m) { wgt[m] = __expf(mt[m] - pmx); zs += wgt[m]; }
  zs += __shfl_xor(zs, 1);
  zs += __shfl_xor(zs, 2);
  zs += __shfl_xor(zs, 4);
  zs += __shfl_xor(zs, 8);
  if (t == 0) { pm_g[b * 128 + tile] = pmx; z_g[b * 128 + tile] = zs; }

  // ---- epilogue: float4 seg1 (c2q), seg2 (c*c2q), q2c partial ----
  const float* cb = c + ((size_t)(b * CL + it0)) * DD;
  float* ob = out + ((size_t)(b * CL + it0)) * (4 * DD);
  #pragma unroll
  for (int n = 0; n < 2; ++n) {
    int d4 = dc + n * 16 + lg * 4;
    f32x4 psum = (f32x4){0.f, 0.f, 0.f, 0.f};
    #pragma unroll
    for (int m = 0; m < 2; ++m) {
      int i = m * 16 + lr;
      f32x4 cv = *(const f32x4*)(cb + (size_t)i * DD + d4);
      f32x4 c2q = o2[m][n] * invz[m];
      float* orow = ob + (size_t)i * (4 * DD);
      *(f32x4*)(orow + DD + d4) = c2q;
      *(f32x4*)(orow + 2 * DD + d4) = cv * c2q;
      psum += wgt[m] * cv;
    }
    #pragma unroll
    for (int j = 0; j < 4; ++j) {
      psum[j] += __shfl_xor(psum[j], 1);
      psum[j] += __shfl_xor(psum[j], 2);
      psum[j] += __shfl_xor(psum[j], 4);
      psum[j] += __shfl_xor(psum[j], 8);
    }
    if (lr == 0)
      *(f32x4*)(part_g + ((size_t)(b * 128 + tile)) * DD + d4) = psum;
  }
}

// ---------------- K2: q2c reduce + seg0 (c) + seg3 (c*q2c) ----------------
// 512 blocks (64 rows each); wk over 128 tiles, redundant per block.
__global__ __launch_bounds__(256) void q2c_seg3_k(
    const float* __restrict__ c,
    const float* __restrict__ pm_g, const float* __restrict__ z_g,
    const float* __restrict__ part_g, float* __restrict__ out)
{
  __shared__ float wk[128];
  __shared__ float rm[2];
  __shared__ float rz[2];
  int blk = blockIdx.x;
  int b = blk & 7;
  int chunk = blk >> 3;          // 0..63, each 64 rows
  int t = threadIdx.x;

  float p = (t < 128) ? pm_g[b * 128 + t] : -1e30f;
  if (t < 128) {
    float m = p;
    #pragma unroll
    for (int o = 1; o < 64; o <<= 1) m = fmaxf(m, __shfl_xor(m, o));
    if ((t & 63) == 0) rm[t >> 6] = m;
  }
  __syncthreads();
  float M = fmaxf(rm[0], rm[1]);
  if (t < 128) {
    float ew = __expf(p - M);
    float zi = ew * z_g[b * 128 + t];
    float s = zi;
    #pragma unroll
    for (int o = 1; o < 64; o <<= 1) s += __shfl_xor(s, o);
    if ((t & 63) == 0) rz[t >> 6] = s;
    wk[t] = ew;
  }
  __syncthreads();
  float Zinv = 1.0f / (rz[0] + rz[1]);

  int c4 = (t & 63) * 4;
  f32x4 g = (f32x4){0.f, 0.f, 0.f, 0.f};
  #pragma unroll 8
  for (int k = 0; k < 128; ++k)
    g += wk[k] * *(const f32x4*)(part_g + ((size_t)(b * 128 + k)) * DD + c4);
  g *= Zinv;

  int r0 = chunk * 64 + (t >> 6);
  for (int it = 0; it < 16; ++it) {
    int row = r0 + it * 4;
    f32x4 cv = *(const f32x4*)(c + ((size_t)(b * CL + row)) * DD + c4);
    float* orow = out + ((size_t)(b * CL + row)) * (4 * DD);
    *(f32x4*)(orow + c4) = cv;                 // segment 0
    *(f32x4*)(orow + 3 * DD + c4) = cv * g;    // segment 3
  }
}

extern "C" void kernel_launch(void* const* d_in, const int* in_sizes, int n_in,
                              void* d_out, int out_size, void* d_ws, size_t ws_size,
                              hipStream_t stream) {
  const float* q = (const float*)d_in[0];
  const float* c = (const float*)d_in[1];
  const float* w = (const float*)d_in[2];
  float* out = (float*)d_out;
  char* ws = (char*)d_ws;

  u16*   qbf  = (u16*)(ws);                    // 2,097,152 B
  u8*    qt8  = (u8*)(ws + 2097152);           // 1,048,576 B
  float* qw   = (float*)(ws + 3145728);        //    16,384 B
  float* pm   = (float*)(ws + 3162112);        //     4,096 B
  float* zb   = (float*)(ws + 3166208);        //     4,096 B
  float* part = (float*)(ws + 3170304);        // 1,048,576 B

  prep_q_k<<<512, 256, 0, stream>>>(q, w, qbf, qt8, qw);
  attn_main_k<<<1024, 512, 0, stream>>>(c, w, qbf, qt8, qw, pm, zb, part, out);
  q2c_seg3_k<<<512, 256, 0, stream>>>(c, pm, zb, part, out);
}

// Round 19
// 83.681 us; speedup vs baseline: 1.2832x; 1.2832x over previous
//
#include <hip/hip_runtime.h>

#define BB 8
#define CL 4096
#define QL 512
#define DD 256

typedef unsigned short u16;
typedef unsigned char u8;
typedef long long i64;
typedef unsigned int u32;
typedef float f32x4 __attribute__((ext_vector_type(4)));
typedef short s16x8 __attribute__((ext_vector_type(8)));

static __device__ __forceinline__ u16 f2bf(float x) {
  unsigned int u = __float_as_uint(x);
  u += 0x7FFFu + ((u >> 16) & 1u);
  return (u16)(u >> 16);
}
static __device__ __forceinline__ float bf2f(u16 h) {
  return __uint_as_float(((unsigned int)h) << 16);
}

// ---------------- K0: prep q (bf16 row-major, fp8 transposed, qw dots) ----
__global__ __launch_bounds__(256) void prep_q_k(
    const float* __restrict__ q, const float* __restrict__ w,
    u16* __restrict__ qbf, u8* __restrict__ qt8, float* __restrict__ qw_g)
{
  __shared__ u16 qs[8][256];
  __shared__ float red[8][32];
  int blk = blockIdx.x;
  int b = blk & 7;
  int j0 = (blk >> 3) * 8;
  int t = threadIdx.x;
  int r = t >> 5;
  int cs = (t & 31) * 8;

  const float* qrow = q + ((size_t)(b * QL + j0 + r)) * DD + cs;
  float4 v0 = *(const float4*)(qrow);
  float4 v1 = *(const float4*)(qrow + 4);
  float4 w0 = *(const float4*)(w + cs);       // w_q
  float4 w1 = *(const float4*)(w + cs + 4);
  float pw = v0.x*w0.x + v0.y*w0.y + v0.z*w0.z + v0.w*w0.w
           + v1.x*w1.x + v1.y*w1.y + v1.z*w1.z + v1.w*w1.w;

  union { u16 u[8]; uint4 v; } pk;
  pk.u[0]=f2bf(v0.x); pk.u[1]=f2bf(v0.y); pk.u[2]=f2bf(v0.z); pk.u[3]=f2bf(v0.w);
  pk.u[4]=f2bf(v1.x); pk.u[5]=f2bf(v1.y); pk.u[6]=f2bf(v1.z); pk.u[7]=f2bf(v1.w);

  *(uint4*)(qbf + ((size_t)(b * QL + j0 + r)) * DD + cs) = pk.v;
  *(uint4*)(&qs[r][cs]) = pk.v;
  red[r][t & 31] = pw;
  __syncthreads();

  if (t < 8) {
    float s = 0.f;
    #pragma unroll
    for (int k = 0; k < 32; ++k) s += red[t][k];
    qw_g[b * QL + j0 + t] = s;
  }

  int d = t;
  float f[8];
  #pragma unroll
  for (int jj = 0; jj < 8; ++jj) f[jj] = bf2f(qs[jj][d]);
  unsigned int lo = __builtin_amdgcn_cvt_pk_fp8_f32(f[0], f[1], 0u, false);
  lo = __builtin_amdgcn_cvt_pk_fp8_f32(f[2], f[3], lo, true);
  unsigned int hi = __builtin_amdgcn_cvt_pk_fp8_f32(f[4], f[5], 0u, false);
  hi = __builtin_amdgcn_cvt_pk_fp8_f32(f[6], f[7], hi, true);
  *(unsigned int*)(qt8 + ((size_t)(b * DD + d)) * QL + j0) = lo;
  *(unsigned int*)(qt8 + ((size_t)(b * DD + d)) * QL + j0 + 4) = hi;
}

// ---------------- K1: 64-row c tile, 8 waves, fp8 P aliased over cm -------
// (512,2): grid supplies exactly 2 blocks/CU, so this bound costs nothing
// and gives the allocator a 256-VGPR budget for deeper load scheduling.
__global__ __launch_bounds__(512, 2) void attn_main_k(
    const float* __restrict__ c, const float* __restrict__ w,
    const u16* __restrict__ qbf, const u8* __restrict__ qt8,
    const float* __restrict__ qw_g,
    float* __restrict__ pm_g, float* __restrict__ z_g,
    float* __restrict__ part_g, float* __restrict__ out)
{
  __shared__ u8 pool8[64 * 512];     // cm bf16 view [64][256] / P fp8 [64][512]
  __shared__ float qw_s[QL];
  __shared__ float cw_s[64];
  __shared__ float red_m[64][8];     // [row][wave]
  __shared__ float red_z[64][8];

  u16* cm = (u16*)pool8;

  int t = threadIdx.x;
  int blk = blockIdx.x;
  int b = blk & 7;
  int tile = blk >> 3;               // 0..63
  int it0 = tile * 64;

  int wv = t >> 6;                   // 0..7
  int ln = t & 63;
  int lr = ln & 15;
  int lg = ln >> 4;
  int jc = wv * 64;                  // GEMM1 j-chunk
  int aswz = (lr & 7) << 3;

  // ---- staging: c tile -> cm bf16 (swizzled), cw dots (NO seg0 stores) ---
  {
    int r = t >> 3;
    int cg = (t & 7) * 32;
    int swz = (r & 7) << 3;
    const float* crow = c + ((size_t)(b * CL + it0 + r)) * DD + cg;
    float pcw = 0.f;
    #pragma unroll
    for (int u = 0; u < 32; u += 4) {
      f32x4 cv  = *(const f32x4*)(crow + u);
      f32x4 wcv = *(const f32x4*)(w + DD + cg + u);      // w_c
      f32x4 wmv = *(const f32x4*)(w + 2 * DD + cg + u);  // w_m
      pcw += cv[0]*wcv[0] + cv[1]*wcv[1] + cv[2]*wcv[2] + cv[3]*wcv[3];
      ushort4 hv;
      hv.x = f2bf(cv[0] * wmv[0]); hv.y = f2bf(cv[1] * wmv[1]);
      hv.z = f2bf(cv[2] * wmv[2]); hv.w = f2bf(cv[3] * wmv[3]);
      *(ushort4*)(&cm[r * 256 + ((cg + u) ^ swz)]) = hv;
    }
    pcw += __shfl_xor(pcw, 1);
    pcw += __shfl_xor(pcw, 2);
    pcw += __shfl_xor(pcw, 4);
    if ((t & 7) == 0) cw_s[r] = pcw;
    qw_s[t] = qw_g[b * QL + t];
  }
  __syncthreads();   // bar 1: cm/cw/qw ready

  // ---- GEMM1 (swapped): acc[m][n][rr] = S'[i=m*16+lr][j=jc+n*16+lg*4+rr] --
  f32x4 acc[4][4];
  #pragma unroll
  for (int m = 0; m < 4; ++m)
    #pragma unroll
    for (int n = 0; n < 4; ++n) acc[m][n] = (f32x4){0.f, 0.f, 0.f, 0.f};

  const u16* qb = qbf + (size_t)b * QL * DD + (size_t)(jc + lr) * DD + lg * 8;
  #pragma unroll
  for (int kk = 0; kk < 8; ++kk) {
    s16x8 a[4];
    #pragma unroll
    for (int m = 0; m < 4; ++m)
      a[m] = *(const s16x8*)(&cm[(m * 16 + lr) * 256 + ((kk * 32 + lg * 8) ^ aswz)]);
    #pragma unroll
    for (int nh = 0; nh < 4; nh += 2) {
      s16x8 bq0 = *(const s16x8*)(qb + (size_t)(nh * 16) * DD + kk * 32);
      s16x8 bq1 = *(const s16x8*)(qb + (size_t)((nh + 1) * 16) * DD + kk * 32);
      #pragma unroll
      for (int m = 0; m < 4; ++m) {
        acc[m][nh]     = __builtin_amdgcn_mfma_f32_16x16x32_bf16(bq0, a[m], acc[m][nh], 0, 0, 0);
        acc[m][nh + 1] = __builtin_amdgcn_mfma_f32_16x16x32_bf16(bq1, a[m], acc[m][nh + 1], 0, 0, 0);
      }
    }
  }

  // ---- merged softmax (no-max): bias, exp in-register, per-wave partials -
  #pragma unroll
  for (int m = 0; m < 4; ++m) {
    float mx = -1e30f;
    float s = 0.f;
    #pragma unroll
    for (int n = 0; n < 4; ++n) {
      f32x4 qq = *(const f32x4*)(&qw_s[jc + n * 16 + lg * 4]);
      #pragma unroll
      for (int rr = 0; rr < 4; ++rr) {
        float sv = acc[m][n][rr] + qq[rr];
        mx = fmaxf(mx, sv);
        float e = __expf(sv);
        acc[m][n][rr] = e;
        s += e;
      }
    }
    mx = fmaxf(mx, __shfl_xor(mx, 16));
    mx = fmaxf(mx, __shfl_xor(mx, 32));
    s += __shfl_xor(s, 16);
    s += __shfl_xor(s, 32);
    if (lg == 0) { red_m[m * 16 + lr][wv] = mx; red_z[m * 16 + lr][wv] = s; }
  }
  __syncthreads();   // bar 2: cm reads done -> pool reusable as P

  // ---- P-write: fp8 packed (4 consecutive j per dword), swizzled ----
  #pragma unroll
  for (int m = 0; m < 4; ++m) {
    int row = m * 16 + lr;
    size_t rb = (size_t)row * 512;
    #pragma unroll
    for (int n = 0; n < 4; ++n) {
      unsigned int p4 = __builtin_amdgcn_cvt_pk_fp8_f32(acc[m][n][0], acc[m][n][1], 0u, false);
      p4 = __builtin_amdgcn_cvt_pk_fp8_f32(acc[m][n][2], acc[m][n][3], p4, true);
      *(unsigned int*)(pool8 + rb + (((unsigned)(jc + n * 16 + lg * 4)) ^ aswz)) = p4;
    }
  }
  __syncthreads();   // bar 3: P ready

  // ---- GEMM2 (fp8, swapped): o2[m][n] = c2q[i=m*16+lr][d=dc+n*16+lg*4..] -
  f32x4 o2[4][2];
  #pragma unroll
  for (int m = 0; m < 4; ++m)
    #pragma unroll
    for (int n = 0; n < 2; ++n) o2[m][n] = (f32x4){0.f, 0.f, 0.f, 0.f};

  int dc = wv * 32;
  const u8* qt = qt8 + (size_t)b * DD * QL + (size_t)(dc + lr) * QL + lg * 8;
  #pragma unroll
  for (int kk = 0; kk < 16; ++kk) {
    i64 bv0 = *(const i64*)(qt + kk * 32);
    i64 bv1 = *(const i64*)(qt + (size_t)16 * QL + kk * 32);
    i64 pa[4];
    #pragma unroll
    for (int m = 0; m < 4; ++m)
      pa[m] = *(const i64*)(pool8 + (size_t)(m * 16 + lr) * 512 + (((unsigned)(kk * 32 + lg * 8)) ^ aswz));
    #pragma unroll
    for (int m = 0; m < 4; ++m) {
      o2[m][0] = __builtin_amdgcn_mfma_f32_16x16x32_fp8_fp8(bv0, pa[m], o2[m][0], 0, 0, 0);
      o2[m][1] = __builtin_amdgcn_mfma_f32_16x16x32_fp8_fp8(bv1, pa[m], o2[m][1], 0, 0, 0);
    }
  }

  // ---- per-thread row stats (red_* ordered by bars 2/3) ----
  float invz[4], wgt[4], mt[4];
  float pmx = -1e30f;
  #pragma unroll
  for (int m = 0; m < 4; ++m) {
    int i = m * 16 + lr;
    float4 m0 = *(const float4*)(&red_m[i][0]);
    float4 m1 = *(const float4*)(&red_m[i][4]);
    mt[m] = cw_s[i] + fmaxf(fmaxf(fmaxf(m0.x, m0.y), fmaxf(m0.z, m0.w)),
                            fmaxf(fmaxf(m1.x, m1.y), fmaxf(m1.z, m1.w)));
    pmx = fmaxf(pmx, mt[m]);
    float4 z0 = *(const float4*)(&red_z[i][0]);
    float4 z1 = *(const float4*)(&red_z[i][4]);
    invz[m] = 1.0f / (z0.x + z0.y + z0.z + z0.w + z1.x + z1.y + z1.z + z1.w);
  }
  pmx = fmaxf(pmx, __shfl_xor(pmx, 1));
  pmx = fmaxf(pmx, __shfl_xor(pmx, 2));
  pmx = fmaxf(pmx, __shfl_xor(pmx, 4));
  pmx = fmaxf(pmx, __shfl_xor(pmx, 8));
  float zs = 0.f;
  #pragma unroll
  for (int m = 0; m < 4; ++m) { wgt[m] = __expf(mt[m] - pmx); zs += wgt[m]; }
  zs += __shfl_xor(zs, 1);
  zs += __shfl_xor(zs, 2);
  zs += __shfl_xor(zs, 4);
  zs += __shfl_xor(zs, 8);
  if (t == 0) { pm_g[b * 64 + tile] = pmx; z_g[b * 64 + tile] = zs; }

  // ---- epilogue: float4 seg1 (c2q), seg2 (c*c2q), q2c partial ----
  const float* cb = c + ((size_t)(b * CL + it0)) * DD;
  float* ob = out + ((size_t)(b * CL + it0)) * (4 * DD);
  #pragma unroll
  for (int n = 0; n < 2; ++n) {
    int d4 = dc + n * 16 + lg * 4;
    f32x4 psum = (f32x4){0.f, 0.f, 0.f, 0.f};
    #pragma unroll
    for (int m = 0; m < 4; ++m) {
      int i = m * 16 + lr;
      f32x4 cv = *(const f32x4*)(cb + (size_t)i * DD + d4);
      f32x4 c2q = o2[m][n] * invz[m];
      float* orow = ob + (size_t)i * (4 * DD);
      *(f32x4*)(orow + DD + d4) = c2q;
      *(f32x4*)(orow + 2 * DD + d4) = cv * c2q;
      psum += wgt[m] * cv;
    }
    #pragma unroll
    for (int j = 0; j < 4; ++j) {
      psum[j] += __shfl_xor(psum[j], 1);
      psum[j] += __shfl_xor(psum[j], 2);
      psum[j] += __shfl_xor(psum[j], 4);
      psum[j] += __shfl_xor(psum[j], 8);
    }
    if (lr == 0)
      *(f32x4*)(part_g + ((size_t)(b * 64 + tile)) * DD + d4) = psum;
  }
}

// ---------------- K2: q2c reduce + seg0 (c) + seg3 (c*q2c) ----------------
// 512 blocks (64 rows each) for write parallelism; wk redundant per block.
__global__ __launch_bounds__(256) void q2c_seg3_k(
    const float* __restrict__ c,
    const float* __restrict__ pm_g, const float* __restrict__ z_g,
    const float* __restrict__ part_g, float* __restrict__ out)
{
  __shared__ float wk[64];
  int blk = blockIdx.x;
  int b = blk & 7;
  int chunk = blk >> 3;          // 0..63, each 64 rows
  int t = threadIdx.x;

  if (t < 64) {
    float p = pm_g[b * 64 + t];
    float m = p;
    #pragma unroll
    for (int o = 1; o < 64; o <<= 1) m = fmaxf(m, __shfl_xor(m, o));
    float ew = __expf(p - m);
    float zi = ew * z_g[b * 64 + t];
    float s = zi;
    #pragma unroll
    for (int o = 1; o < 64; o <<= 1) s += __shfl_xor(s, o);
    wk[t] = ew / s;
  }
  __syncthreads();

  int c4 = (t & 63) * 4;
  f32x4 g = (f32x4){0.f, 0.f, 0.f, 0.f};
  #pragma unroll 8
  for (int k = 0; k < 64; ++k)
    g += wk[k] * *(const f32x4*)(part_g + ((size_t)(b * 64 + k)) * DD + c4);

  int r0 = chunk * 64 + (t >> 6);
  for (int it = 0; it < 16; ++it) {
    int row = r0 + it * 4;
    f32x4 cv = *(const f32x4*)(c + ((size_t)(b * CL + row)) * DD + c4);
    float* orow = out + ((size_t)(b * CL + row)) * (4 * DD);
    *(f32x4*)(orow + c4) = cv;                 // segment 0
    *(f32x4*)(orow + 3 * DD + c4) = cv * g;    // segment 3
  }
}

extern "C" void kernel_launch(void* const* d_in, const int* in_sizes, int n_in,
                              void* d_out, int out_size, void* d_ws, size_t ws_size,
                              hipStream_t stream) {
  const float* q = (const float*)d_in[0];
  const float* c = (const float*)d_in[1];
  const float* w = (const float*)d_in[2];
  float* out = (float*)d_out;
  char* ws = (char*)d_ws;

  u16*   qbf  = (u16*)(ws);                    // 2,097,152 B
  u8*    qt8  = (u8*)(ws + 2097152);           // 1,048,576 B
  float* qw   = (float*)(ws + 3145728);        //    16,384 B
  float* pm   = (float*)(ws + 3162112);        //     2,048 B
  float* zb   = (float*)(ws + 3164160);        //     2,048 B
  float* part = (float*)(ws + 3166208);        //   524,288 B

  prep_q_k<<<512, 256, 0, stream>>>(q, w, qbf, qt8, qw);
  attn_main_k<<<512, 512, 0, stream>>>(c, w, qbf, qt8, qw, pm, zb, part, out);
  q2c_seg3_k<<<512, 256, 0, stream>>>(c, pm, zb, part, out);
}